// Round 1
// baseline (530.500 us; speedup 1.0000x reference)
//
#include <hip/hip_runtime.h>

// SoftPool2d: x (16, 96, 256, 256) f32, 2x2 window, stride 2, no pad.
// out (16, 96, 128, 128) f32. out[p] = sum(t_i * softmax(t)_i) over 4 taps.
//
// Memory-bound streaming kernel: each thread handles 2 adjacent output
// pixels -> float4 load from each of the two input rows (16 B/lane,
// coalesced), float2 store.

#define H_IN   256
#define W_IN   256
#define H_OUT  128
#define W_OUT  128

__device__ __forceinline__ float softpool4(float a, float b, float c, float d) {
    float m  = fmaxf(fmaxf(a, b), fmaxf(c, d));
    float ea = __expf(a - m);
    float eb = __expf(b - m);
    float ec = __expf(c - m);
    float ed = __expf(d - m);
    return (a * ea + b * eb + c * ec + d * ed) / (ea + eb + ec + ed);
}

__global__ __launch_bounds__(256)
void SoftPool2d_850403524762_kernel(const float* __restrict__ x,
                                    float* __restrict__ out,
                                    int n_pairs) {
    int tid = blockIdx.x * blockDim.x + threadIdx.x;
    if (tid >= n_pairs) return;

    // 64 pairs per 128-wide output row
    int wo2 = tid & 63;        // pair index within row
    int r   = tid >> 6;        // flattened (b*c*H_OUT + ho)
    int ho  = r & (H_OUT - 1);
    int bc  = r >> 7;

    const float* row0 = x + (size_t)bc * (H_IN * W_IN)
                          + (size_t)(2 * ho) * W_IN
                          + 4 * wo2;

    const float4 t0 = *(const float4*)(row0);         // input row 2*ho
    const float4 t1 = *(const float4*)(row0 + W_IN);  // input row 2*ho+1

    float2 o;
    o.x = softpool4(t0.x, t0.y, t1.x, t1.y);
    o.y = softpool4(t0.z, t0.w, t1.z, t1.w);

    float* op = out + (size_t)r * W_OUT + 2 * wo2;
    *(float2*)op = o;
}

extern "C" void kernel_launch(void* const* d_in, const int* in_sizes, int n_in,
                              void* d_out, int out_size, void* d_ws, size_t ws_size,
                              hipStream_t stream) {
    const float* x  = (const float*)d_in[0];
    float* out      = (float*)d_out;

    // 16 * 96 * 128 * 128 output pixels, 2 per thread
    const int n_pairs = 16 * 96 * H_OUT * (W_OUT / 2);   // 12,582,912
    const int block   = 256;
    const int grid    = (n_pairs + block - 1) / block;   // 49,152

    SoftPool2d_850403524762_kernel<<<grid, block, 0, stream>>>(x, out, n_pairs);
}

// Round 3
// 516.293 us; speedup vs baseline: 1.0275x; 1.0275x over previous
//
#include <hip/hip_runtime.h>

// SoftPool2d: x (16, 96, 256, 256) f32, 2x2 window, stride 2, no pad.
// out (16, 96, 128, 128) f32. out[p] = sum(t_i * softmax(t)_i) over 4 taps.
//
// Streaming, memory-bound. Each thread: 2x8 input patch -> 4 output pixels.
//   - four nontemporal 16 B loads (4 in flight for memory-level parallelism)
//   - one nontemporal 16 B store (full-width)
//   - softmax via max-sub + __expf, reciprocal via v_rcp_f32 (tolerance 0.103)
//
// NOTE: __builtin_nontemporal_* requires a native vector type, not HIP's
// float4 struct -> use ext_vector_type(4).

#define H_IN   256
#define W_IN   256
#define H_OUT  128
#define W_OUT  128

typedef float f32x4 __attribute__((ext_vector_type(4)));

__device__ __forceinline__ float softpool4(float a, float b, float c, float d) {
    float m  = fmaxf(fmaxf(a, b), fmaxf(c, d));
    float ea = __expf(a - m);
    float eb = __expf(b - m);
    float ec = __expf(c - m);
    float ed = __expf(d - m);
    float num = a * ea + b * eb + c * ec + d * ed;
    float den = (ea + eb) + (ec + ed);
    return num * __builtin_amdgcn_rcpf(den);
}

__global__ __launch_bounds__(256)
void SoftPool2d_850403524762_kernel(const float* __restrict__ x,
                                    float* __restrict__ out,
                                    int n_quads) {
    int tid = blockIdx.x * blockDim.x + threadIdx.x;
    if (tid >= n_quads) return;

    // 32 quads per 128-wide output row
    int wq = tid & 31;         // quad index within output row
    int r  = tid >> 5;         // flattened (b*c*H_OUT + ho)
    int ho = r & (H_OUT - 1);
    int bc = r >> 7;

    const float* p = x + (size_t)bc * (H_IN * W_IN)
                       + (size_t)(2 * ho) * W_IN
                       + 8 * wq;

    // 2 rows x 8 cols: 4 independent 16 B loads
    const f32x4 a0 = __builtin_nontemporal_load((const f32x4*)(p));
    const f32x4 a1 = __builtin_nontemporal_load((const f32x4*)(p + 4));
    const f32x4 b0 = __builtin_nontemporal_load((const f32x4*)(p + W_IN));
    const f32x4 b1 = __builtin_nontemporal_load((const f32x4*)(p + W_IN + 4));

    f32x4 o;
    o.x = softpool4(a0.x, a0.y, b0.x, b0.y);
    o.y = softpool4(a0.z, a0.w, b0.z, b0.w);
    o.z = softpool4(a1.x, a1.y, b1.x, b1.y);
    o.w = softpool4(a1.z, a1.w, b1.z, b1.w);

    float* op = out + (size_t)r * W_OUT + 4 * wq;
    __builtin_nontemporal_store(o, (f32x4*)op);
}

extern "C" void kernel_launch(void* const* d_in, const int* in_sizes, int n_in,
                              void* d_out, int out_size, void* d_ws, size_t ws_size,
                              hipStream_t stream) {
    const float* x  = (const float*)d_in[0];
    float* out      = (float*)d_out;

    // 16 * 96 * 128 * 128 output pixels, 4 per thread
    const int n_quads = 16 * 96 * H_OUT * (W_OUT / 4);   // 6,291,456
    const int block   = 256;
    const int grid    = (n_quads + block - 1) / block;   // 24,576

    SoftPool2d_850403524762_kernel<<<grid, block, 0, stream>>>(x, out, n_quads);
}